// Round 1
// baseline (413.170 us; speedup 1.0000x reference)
//
#include <hip/hip_runtime.h>
#include <math.h>

#define B 16
#define C 8
#define H 512
#define W 512
#define HW (H * W)
#define CHW (C * H * W)

__device__ __forceinline__ float sigmoidf_fast(float x) {
    return __fdividef(1.0f, 1.0f + __expf(-x));
}

// t is exactly 0.0 or 1.0 (Bernoulli). BCE elem = -(t*clip(log p) + (1-t)*clip(log(1-p)))
//                                             = -max(log(t ? p : 1-p), -100)
__device__ __forceinline__ float bce_term(float t, float p) {
    float q = (t > 0.5f) ? p : (1.0f - p);
    return -fmaxf(__logf(q), -100.0f);
}

__global__ __launch_bounds__(256) void bicon_loss_kernel(
    const float* __restrict__ c_map,
    const float* __restrict__ target,
    const float* __restrict__ con_target,
    float* __restrict__ out)
{
    const int tid = blockIdx.x * 256 + threadIdx.x;   // pixel index in (B,H,W)
    const int w      = tid & (W - 1);
    const int hw_idx = tid & (HW - 1);
    const int h      = hw_idx >> 9;          // / W
    const int b      = tid >> 18;            // / HW

    const float* cm = c_map      + b * CHW + hw_idx;  // [b, 0, h, w]
    const float* ct = con_target + b * CHW + hw_idx;

    // center sigmoids
    float p[8];
    #pragma unroll
    for (int c = 0; c < 8; ++c) p[c] = sigmoidf_fast(cm[c * HW]);

    // neighbor p (shifted-in zeros at boundaries)
    auto nb = [&](int c, int dh, int dw) -> float {
        const bool ok = ((unsigned)(h + dh) < (unsigned)H) &&
                        ((unsigned)(w + dw) < (unsigned)W);
        const int off = ok ? (dh * W + dw) : 0;       // clamp to safe address
        const float v = cm[c * HW + off];
        return ok ? sigmoidf_fast(v) : 0.0f;
    };

    const float a1 = p[3] * nb(4,  0, -1);   // c3 * shift_right(c4)
    const float a2 = p[4] * nb(3,  0, +1);   // c4 * shift_left(c3)
    const float a3 = p[1] * nb(6, -1,  0);   // c1 * shift_down(c6)
    const float a4 = p[6] * nb(1, +1,  0);   // c6 * shift_up(c1)
    const float a5 = p[2] * nb(5, -1, +1);   // c2 * shift_left(shift_down(c5))
    const float a6 = p[5] * nb(2, +1, -1);   // c5 * shift_right(shift_up(c2))
    const float a7 = p[0] * nb(7, -1, -1);   // c0 * shift_right(shift_down(c7))
    const float a8 = p[7] * nb(0, +1, +1);   // c7 * shift_left(shift_up(c0))

    // stack order in reference: [a7, a3, a5, a1, a2, a6, a4, a8]
    const float vote[8] = { a7, a3, a5, a1, a2, a6, a4, a8 };

    float ctv[8];
    float sum_conn = 0.0f;
    #pragma unroll
    for (int c = 0; c < 8; ++c) { ctv[c] = ct[c * HW]; sum_conn += ctv[c]; }

    float local = 0.0f;
    #pragma unroll
    for (int c = 0; c < 8; ++c) {
        local += 0.8f * bce_term(ctv[c], p[c]);
        local += 0.2f * bce_term(ctv[c], vote[c]);
    }

    const float glo = (a1 + a2 + a3 + a4 + a5 + a6 + a7 + a8) * 0.125f;
    float mn = vote[0];
    #pragma unroll
    for (int c = 1; c < 8; ++c) mn = fminf(mn, vote[c]);

    const bool edge = (sum_conn < 8.0f) && (sum_conn > 0.0f);
    const float dec = edge ? (1.0f - mn) : glo;

    const float t = target[b * HW + hw_idx];
    local += bce_term(t, dec);

    // ---- reduction: wave64 shuffle -> LDS -> one atomic per block ----
    #pragma unroll
    for (int off = 32; off > 0; off >>= 1)
        local += __shfl_down(local, off, 64);

    __shared__ float wsum[4];
    const int lane = threadIdx.x & 63;
    const int wid  = threadIdx.x >> 6;
    if (lane == 0) wsum[wid] = local;
    __syncthreads();
    if (threadIdx.x == 0) {
        const float s = wsum[0] + wsum[1] + wsum[2] + wsum[3];
        atomicAdd(out, s);
    }
}

extern "C" void kernel_launch(void* const* d_in, const int* in_sizes, int n_in,
                              void* d_out, int out_size, void* d_ws, size_t ws_size,
                              hipStream_t stream) {
    const float* c_map      = (const float*)d_in[0];
    const float* target     = (const float*)d_in[1];
    const float* con_target = (const float*)d_in[2];
    float* out = (float*)d_out;

    hipMemsetAsync(out, 0, sizeof(float), stream);   // out is poisoned 0xAA before every launch

    const int total  = B * HW;            // 4,194,304 pixels
    const int blocks = total / 256;       // 16384
    bicon_loss_kernel<<<blocks, 256, 0, stream>>>(c_map, target, con_target, out);
}

// Round 2
// 292.703 us; speedup vs baseline: 1.4116x; 1.4116x over previous
//
#include <hip/hip_runtime.h>
#include <math.h>

#define NB 16
#define NC 8
#define HH 512
#define WW 512
#define HW (HH * WW)
#define CHW (NC * HW)

__device__ __forceinline__ float sigf(float x) {
    return __fdividef(1.0f, 1.0f + __expf(-x));
}

// t is exactly 0.0 or 1.0: BCE elem = -max(log(t ? p : 1-p), -100)
__device__ __forceinline__ float bce_term(float t, float p) {
    float q = (t > 0.5f) ? p : (1.0f - p);
    return -fmaxf(__logf(q), -100.0f);
}

__device__ __forceinline__ void ld4(const float* p, float* o) {
    float4 v = *(const float4*)p;
    o[0] = v.x; o[1] = v.y; o[2] = v.z; o[3] = v.w;
}

__global__ __launch_bounds__(256) void bicon_loss_kernel(
    const float* __restrict__ c_map,
    const float* __restrict__ target,
    const float* __restrict__ con_target,
    float* __restrict__ out)
{
    const int tid = blockIdx.x * 256 + threadIdx.x;   // one thread = 4 pixels along w
    const int w0 = (tid & 127) << 2;                  // 128 groups of 4 per row
    const int h  = (tid >> 7) & (HH - 1);
    const int b  = tid >> 16;

    const float* cm = c_map      + b * CHW + h * WW + w0;
    const float* ct = con_target + b * CHW + h * WW + w0;

    const bool hu = (h > 0), hd = (h < HH - 1);       // wave-uniform
    const bool wl = (w0 > 0), wr = (w0 + 4 < WW);     // false only at lane 0 / 63 of edge waves
    const int ru = hu ? -WW : 0;                      // clamped row offsets (safe addresses)
    const int rd = hd ?  WW : 0;

    // ---- all global loads issued up front (23 x dwordx4 + 6 x dword) ----
    float cv[8][4];
    #pragma unroll
    for (int c = 0; c < 8; ++c) ld4(cm + c * HW, cv[c]);

    float u6r[4], u5r[4], u7r[4];                     // row h-1: c6(dw0), c5(dw+1), c7(dw-1)
    ld4(cm + 6 * HW + ru, u6r);
    ld4(cm + 5 * HW + ru, u5r);
    ld4(cm + 7 * HW + ru, u7r);
    const float u5e = cm[5 * HW + ru + (wr ? 4 : 0)];
    const float u7e = cm[7 * HW + ru + (wl ? -1 : 0)];

    float d1r[4], d2r[4], d0r[4];                     // row h+1: c1(dw0), c2(dw+1), c0(dw-1)
    ld4(cm + 1 * HW + rd, d1r);
    ld4(cm + 2 * HW + rd, d2r);
    ld4(cm + 0 * HW + rd, d0r);
    const float d2e = cm[2 * HW + rd + (wr ? 4 : 0)];
    const float d0e = cm[0 * HW + rd + (wl ? -1 : 0)];

    const float m4e = cm[4 * HW + (wl ? -1 : 0)];     // row h edges: c4 @ w0-1, c3 @ w0+4
    const float m3e = cm[3 * HW + (wr ? 4 : 0)];

    float tv[8][4];
    #pragma unroll
    for (int c = 0; c < 8; ++c) ld4(ct + c * HW, tv[c]);

    float tg[4];
    ld4(target + b * HW + h * WW + w0, tg);

    // ---- center sigmoids ----
    float sp[8][4];
    #pragma unroll
    for (int c = 0; c < 8; ++c)
        #pragma unroll
        for (int j = 0; j < 4; ++j) sp[c][j] = sigf(cv[c][j]);

    float local = 0.0f;
    #pragma unroll
    for (int j = 0; j < 4; ++j) {
        // neighbor p values (zero where the shift pads)
        const float n6 = hu ? sigf(u6r[j]) : 0.0f;
        const float n5 = (j < 3) ? (hu ? sigf(u5r[j + 1]) : 0.0f)
                                 : ((hu && wr) ? sigf(u5e) : 0.0f);
        const float n7 = (j > 0) ? (hu ? sigf(u7r[j - 1]) : 0.0f)
                                 : ((hu && wl) ? sigf(u7e) : 0.0f);
        const float dn1 = hd ? sigf(d1r[j]) : 0.0f;
        const float dn2 = (j < 3) ? (hd ? sigf(d2r[j + 1]) : 0.0f)
                                  : ((hd && wr) ? sigf(d2e) : 0.0f);
        const float dn0 = (j > 0) ? (hd ? sigf(d0r[j - 1]) : 0.0f)
                                  : ((hd && wl) ? sigf(d0e) : 0.0f);
        const float m4 = (j > 0) ? sp[4][j - 1] : (wl ? sigf(m4e) : 0.0f);
        const float m3 = (j < 3) ? sp[3][j + 1] : (wr ? sigf(m3e) : 0.0f);

        const float a1 = sp[3][j] * m4;    // c3 * shift_right(c4)
        const float a2 = sp[4][j] * m3;    // c4 * shift_left(c3)
        const float a3 = sp[1][j] * n6;    // c1 * shift_down(c6)
        const float a4 = sp[6][j] * dn1;   // c6 * shift_up(c1)
        const float a5 = sp[2][j] * n5;    // c2 * l-b(c5)
        const float a6 = sp[5][j] * dn2;   // c5 * r-a(c2)
        const float a7 = sp[0][j] * n7;    // c0 * r-b(c7)
        const float a8 = sp[7][j] * dn0;   // c7 * l-a(c0)

        const float vote[8] = { a7, a3, a5, a1, a2, a6, a4, a8 };

        float sum_conn = 0.0f;
        #pragma unroll
        for (int c = 0; c < 8; ++c) sum_conn += tv[c][j];

        #pragma unroll
        for (int c = 0; c < 8; ++c) {
            local += 0.8f * bce_term(tv[c][j], sp[c][j]);
            local += 0.2f * bce_term(tv[c][j], vote[c]);
        }

        const float glo = (a1 + a2 + a3 + a4 + a5 + a6 + a7 + a8) * 0.125f;
        float mn = vote[0];
        #pragma unroll
        for (int c = 1; c < 8; ++c) mn = fminf(mn, vote[c]);

        const bool edge = (sum_conn < 8.0f) && (sum_conn > 0.0f);
        const float dec = edge ? (1.0f - mn) : glo;
        local += bce_term(tg[j], dec);
    }

    // ---- reduction: wave64 shuffle -> LDS -> one atomic per block ----
    #pragma unroll
    for (int off = 32; off > 0; off >>= 1)
        local += __shfl_down(local, off, 64);

    __shared__ float wsum[4];
    const int lane = threadIdx.x & 63;
    const int wid  = threadIdx.x >> 6;
    if (lane == 0) wsum[wid] = local;
    __syncthreads();
    if (threadIdx.x == 0) {
        atomicAdd(out, wsum[0] + wsum[1] + wsum[2] + wsum[3]);
    }
}

extern "C" void kernel_launch(void* const* d_in, const int* in_sizes, int n_in,
                              void* d_out, int out_size, void* d_ws, size_t ws_size,
                              hipStream_t stream) {
    const float* c_map      = (const float*)d_in[0];
    const float* target     = (const float*)d_in[1];
    const float* con_target = (const float*)d_in[2];
    float* out = (float*)d_out;

    hipMemsetAsync(out, 0, sizeof(float), stream);

    const int total_threads = NB * HH * (WW / 4);   // 1,048,576
    const int blocks = total_threads / 256;         // 4096
    bicon_loss_kernel<<<blocks, 256, 0, stream>>>(c_map, target, con_target, out);
}